// Round 4
// baseline (284.948 us; speedup 1.0000x reference)
//
#include <hip/hip_runtime.h>
#include <stdint.h>

#define NPIX     65536
#define NTHREADS 1024
#define NSLICES  512
#define NFEAT    18
#define EMB      256
#define THRESH_RANK 52428u  // 0.8f*(65536-1) == 52428.0 exactly in f32 => fr == 0
#define GCAP     13824      // gathered-key LDS capacity (54 KB)
#define MAXBINS  20
#define EPT4     16         // float4 iterations per thread

// ---------- sortable key mapping (monotonic with float order) ----------
__device__ __forceinline__ uint32_t f2key(float f) {
  uint32_t u = __float_as_uint(f);
  return u ^ ((u & 0x80000000u) ? 0xFFFFFFFFu : 0x80000000u);
}
__device__ __forceinline__ float key2f(uint32_t k) {
  uint32_t u = (k & 0x80000000u) ? (k ^ 0x80000000u) : ~k;
  return __uint_as_float(u);
}

// ---------------- block-wide helpers (Pass A scan + rare fallback) -------------
__device__ __forceinline__ int findbin(const uint32_t* C, uint32_t r) {
  int lo = 0, hi = 2047;
  while (lo < hi) { int mid = (lo + hi) >> 1; if (C[mid] > r) hi = mid; else lo = mid + 1; }
  return lo;
}

__device__ void scan2048(uint32_t* H, uint32_t* Wsum) {
  int tid = threadIdx.x, lane = tid & 63, wid = tid >> 6;
  uint32_t a1 = H[2 * tid + 1];
  uint32_t v = H[2 * tid] + a1;
  for (int d = 1; d < 64; d <<= 1) {
    uint32_t t = __shfl_up(v, d);
    if (lane >= d) v += t;
  }
  if (lane == 63) Wsum[wid] = v;
  __syncthreads();
  uint32_t woff = 0;
  for (int w = 0; w < wid; ++w) woff += Wsum[w];
  v += woff;
  H[2 * tid + 1] = v;
  H[2 * tid]     = v - a1;
  __syncthreads();
}

__device__ void histpass2(const float* sl, int b1, uint32_t* H) {
  int tid = threadIdx.x;
  __syncthreads();
  H[2 * tid] = 0; H[2 * tid + 1] = 0;
  __syncthreads();
  for (int t = 0; t < 64; ++t) {
    uint32_t k = f2key(sl[tid + t * NTHREADS]);
    if ((int)(k >> 21) == b1) atomicAdd(&H[(k >> 10) & 2047u], 1u);
  }
  __syncthreads();
}
__device__ void histpass3(const float* sl, uint32_t pfx, uint32_t* H) {
  int tid = threadIdx.x;
  __syncthreads();
  H[2 * tid] = 0; H[2 * tid + 1] = 0;
  __syncthreads();
  for (int t = 0; t < 64; ++t) {
    uint32_t k = f2key(sl[tid + t * NTHREADS]);
    if ((k >> 10) == pfx) atomicAdd(&H[k & 1023u], 1u);
  }
  __syncthreads();
}

__device__ uint32_t global_select_key(const float* sl, uint32_t rank, const uint32_t* C1,
                                      uint32_t* H2, uint32_t* Wsum, uint32_t* bel_out) {
  int b1 = findbin(C1, rank);
  uint32_t bel1 = b1 ? C1[b1 - 1] : 0u;
  uint32_t r1 = rank - bel1;
  histpass2(sl, b1, H2); scan2048(H2, Wsum);
  int b2 = findbin(H2, r1);
  uint32_t bel2 = b2 ? H2[b2 - 1] : 0u;
  uint32_t r2 = r1 - bel2;
  histpass3(sl, ((uint32_t)b1 << 11) | (uint32_t)b2, H2); scan2048(H2, Wsum);
  int b3 = findbin(H2, r2);
  uint32_t bel3 = b3 ? H2[b3 - 1] : 0u;
  *bel_out = bel1 + bel2 + bel3;
  return ((uint32_t)b1 << 21) | ((uint32_t)b2 << 10) | (uint32_t)b3;
}

// ---------------- wave-synchronous (wave 0 only) helpers ----------------------
__device__ __forceinline__ int wfind2048(const uint32_t* C, uint32_t r, int lane) {
  unsigned long long m = __ballot(C[lane * 32 + 31] > r);
  int chunk = __builtin_ctzll(m);
  unsigned long long m2 = __ballot((lane < 32) && (C[chunk * 32 + lane] > r));
  int off = __builtin_ctzll(m2);
  return chunk * 32 + off;
}
__device__ __forceinline__ int wfind1024(const uint32_t* C, uint32_t r, int lane) {
  unsigned long long m = __ballot(C[lane * 16 + 15] > r);
  int chunk = __builtin_ctzll(m);
  unsigned long long m2 = __ballot((lane < 16) && (C[chunk * 16 + lane] > r));
  int off = __builtin_ctzll(m2);
  return chunk * 16 + off;
}
__device__ void wscan2048(uint32_t* H, int lane) {
  uint32_t run = 0;
#pragma unroll
  for (int t = 0; t < 32; ++t) run += H[lane * 32 + t];
  uint32_t inc = run;
  for (int d = 1; d < 64; d <<= 1) { uint32_t o = __shfl_up(inc, d); if (lane >= d) inc += o; }
  uint32_t acc = inc - run;
#pragma unroll
  for (int t = 0; t < 32; ++t) { acc += H[lane * 32 + t]; H[lane * 32 + t] = acc; }
}
__device__ void wscan1024(uint32_t* H, int lane) {
  uint32_t run = 0;
#pragma unroll
  for (int t = 0; t < 16; ++t) run += H[lane * 16 + t];
  uint32_t inc = run;
  for (int d = 1; d < 64; d <<= 1) { uint32_t o = __shfl_up(inc, d); if (lane >= d) inc += o; }
  uint32_t acc = inc - run;
#pragma unroll
  for (int t = 0; t < 16; ++t) { acc += H[lane * 16 + t]; H[lane * 16 + t] = acc; }
}

struct SelState { int curBin; int curB2; };

// wave-0-uniform rank -> value; ok=false if bin not gathered (caller falls back)
__device__ float wave_rank_value(uint32_t rank, const uint32_t* C1, const uint32_t* G,
                                 const uint8_t* LUT, const uint32_t* roff, const uint32_t* rcnt,
                                 uint32_t* H2, uint32_t* H3, int lane, SelState* st,
                                 bool* ok, uint32_t* bel_out) {
  int b = wfind2048(C1, rank, lane);
  uint32_t below = b ? C1[b - 1] : 0u;
  int rj = LUT[b];
  if (rj == 0xFF) { *ok = false; return 0.0f; }
  uint32_t base = roff[rj], c = rcnt[rj];
  uint32_t r_in = rank - below;
  if (b != st->curBin) {
#pragma unroll
    for (int t = 0; t < 32; ++t) H2[lane * 32 + t] = 0;
    for (uint32_t i = lane; i < c; i += 64) atomicAdd(&H2[(G[base + i] >> 10) & 2047u], 1u);
    wscan2048(H2, lane);
    st->curBin = b; st->curB2 = -1;
  }
  int b2 = wfind2048(H2, r_in, lane);
  uint32_t bel2 = b2 ? H2[b2 - 1] : 0u;
  uint32_t r2 = r_in - bel2;
  uint32_t pfx = ((uint32_t)b << 11) | (uint32_t)b2;
  if (b2 != st->curB2) {
#pragma unroll
    for (int t = 0; t < 16; ++t) H3[lane * 16 + t] = 0;
    for (uint32_t i = lane; i < c; i += 64) {
      uint32_t k = G[base + i];
      if ((k >> 10) == pfx) atomicAdd(&H3[k & 1023u], 1u);
    }
    wscan1024(H3, lane);
    st->curB2 = b2;
  }
  int b3 = wfind1024(H3, r2, lane);
  *bel_out = below + bel2 + (b3 ? H3[b3 - 1] : 0u);
  *ok = true;
  return key2f(((uint32_t)b << 21) | ((uint32_t)b2 << 10) | (uint32_t)b3);
}

// wave-aggregated gather: one atomic per distinct region per wave-call
__device__ __forceinline__ void gather_one(uint32_t kk, const uint8_t* LUT,
                                           uint32_t* gctr, const uint32_t* roff,
                                           uint32_t* G, int lane) {
  int rj = LUT[kk >> 21];
  unsigned long long act = __ballot(rj != 0xFF);
  while (act) {
    int leader = __builtin_ctzll(act);
    int r = __shfl(rj, leader);
    unsigned long long grp = __ballot(rj == r);
    uint32_t basepos = 0;
    if (lane == leader) basepos = atomicAdd(&gctr[r], (uint32_t)__popcll(grp));
    basepos = __shfl(basepos, leader);
    if (rj == r) {
      uint32_t myrank = (uint32_t)__popcll(grp & ((lane == 0) ? 0ull : ((~0ull) >> (64 - lane))));
      G[roff[r] + basepos + myrank] = kk;
    }
    act &= ~grp;
  }
}

__global__ __launch_bounds__(NTHREADS) void feat_kernel(const float* __restrict__ vol,
                                                        float* __restrict__ feats) {
  __shared__ uint32_t HC1[2048];     // level-1 hist -> inclusive prefix C1
  __shared__ uint32_t HC2[2048];     // level-2 scratch (wave + block fallback)
  __shared__ uint32_t HL3[1024];     // level-3 scratch (wave path)
  __shared__ uint32_t G[GCAP];       // gathered keys
  __shared__ uint8_t  LUT[2048];     // bin -> region id (0xFF = none)
  __shared__ uint32_t Wsum[16];
  __shared__ double   tmpD9[16 * 9];
  __shared__ double   s_red[9];
  __shared__ uint32_t H16[16 * 16];  // per-wave privatized 16-bin histogram
  __shared__ uint32_t smaxkey;
  __shared__ uint32_t s_roff[MAXBINS], s_rcnt[MAXBINS], s_gctr[MAXBINS];
  __shared__ float    s_qA[3], s_qB[3], s_qfr[3];
  __shared__ int      s_qdup[3];
  __shared__ uint32_t s_qfb[6];
  __shared__ float    s_thresh;
  __shared__ uint32_t s_cnlt;
  __shared__ int      s_thr_ok;

  const int tid  = threadIdx.x;
  const int lane = tid & 63;
  const int wid  = tid >> 6;
  const float*  sl  = vol + (size_t)blockIdx.x * NPIX;
  const float4* sl4 = (const float4*)sl;

  // ---- Pass A: level-1 histogram (key>>21) + global max, depth-8 pipeline ----
  HC1[2 * tid] = 0; HC1[2 * tid + 1] = 0;
  if (tid == 0) smaxkey = 0u;
  if (tid < 256) H16[tid] = 0u;
  __syncthreads();
  uint32_t mk = 0u;
  {
    float4 pre[4];
#pragma unroll
    for (int j = 0; j < 4; ++j) pre[j] = sl4[tid + j * NTHREADS];
    for (int c = 0; c < 4; ++c) {
      float4 cur[4];
#pragma unroll
      for (int j = 0; j < 4; ++j) cur[j] = pre[j];
      if (c < 3) {
#pragma unroll
        for (int j = 0; j < 4; ++j) pre[j] = sl4[tid + ((c + 1) * 4 + j) * NTHREADS];
      }
#pragma unroll
      for (int j = 0; j < 4; ++j) {
        float4 f = cur[j];
        uint32_t k0 = f2key(f.x), k1 = f2key(f.y), k2 = f2key(f.z), k3 = f2key(f.w);
        mk = max(mk, max(max(k0, k1), max(k2, k3)));
        atomicAdd(&HC1[k0 >> 21], 1u);
        atomicAdd(&HC1[k1 >> 21], 1u);
        atomicAdd(&HC1[k2 >> 21], 1u);
        atomicAdd(&HC1[k3 >> 21], 1u);
      }
    }
  }
  for (int d = 32; d > 0; d >>= 1) { uint32_t o = __shfl_down(mk, d); mk = max(mk, o); }
  if (lane == 0) atomicMax(&smaxkey, mk);
  __syncthreads();
  scan2048(HC1, Wsum);   // HC1 is now C1

  // ---- planning on wave 0 (uniform; lane 0 writes) ----
  if (tid < 64) {
#pragma unroll
    for (int t = 0; t < 32; ++t) LUT[lane * 32 + t] = 0xFF;
    int b1t = wfind2048(HC1, THRESH_RANK, lane);
    uint32_t clo  = b1t ? HC1[b1t - 1] : 0u;
    uint32_t cmax = min(THRESH_RANK, HC1[b1t] - 1u);
    int nreg = 0; uint32_t total = 0;
#define TRYADD(bb_)                                                            \
    { int _b = (bb_);                                                          \
      if (LUT[_b] == 0xFF) {                                                   \
        uint32_t _c = HC1[_b] - (_b ? HC1[_b - 1] : 0u);                       \
        if (nreg < MAXBINS && total + _c <= GCAP) {                            \
          if (lane == 0) { LUT[_b] = (uint8_t)nreg;                            \
            s_roff[nreg] = total; s_rcnt[nreg] = _c; s_gctr[nreg] = 0u; }      \
          total += _c; ++nreg; } } }
    TRYADD(b1t);
    int ba[3], bb[3];
    const float pp[3] = {0.25f, 0.5f, 0.75f};
#pragma unroll
    for (int qi = 0; qi < 3; ++qi) {
      float p = pp[qi];
      uint32_t rlo = clo  + (uint32_t)(int)floorf(p * ((float)(NPIX - clo)  - 1.0f));
      uint32_t rhi = cmax + (uint32_t)(int)floorf(p * ((float)(NPIX - cmax) - 1.0f)) + 1u;
      if (rhi > NPIX - 1u) rhi = NPIX - 1u;
      if (rlo > rhi) rlo = rhi;
      ba[qi] = wfind2048(HC1, rlo, lane);
      bb[qi] = wfind2048(HC1, rhi, lane);
      if (bb[qi] > ba[qi] + 8) bb[qi] = ba[qi] + 8;
    }
    for (int k = 0; k <= 8; ++k)
      for (int qi = 0; qi < 3; ++qi)
        if (ba[qi] + k <= bb[qi]) TRYADD(ba[qi] + k);
#undef TRYADD
    if (lane == 0) s_thr_ok = (LUT[b1t] != 0xFF) ? 1 : 0;
  }
  __syncthreads();

  // ---- gather pass: depth-8 pipeline + wave-aggregated region append ----
  {
    float4 pre[4];
#pragma unroll
    for (int j = 0; j < 4; ++j) pre[j] = sl4[tid + j * NTHREADS];
    for (int c = 0; c < 4; ++c) {
      float4 cur[4];
#pragma unroll
      for (int j = 0; j < 4; ++j) cur[j] = pre[j];
      if (c < 3) {
#pragma unroll
        for (int j = 0; j < 4; ++j) pre[j] = sl4[tid + ((c + 1) * 4 + j) * NTHREADS];
      }
#pragma unroll
      for (int j = 0; j < 4; ++j) {
        float4 f = cur[j];
        gather_one(f2key(f.x), LUT, s_gctr, s_roff, G, lane);
        gather_one(f2key(f.y), LUT, s_gctr, s_roff, G, lane);
        gather_one(f2key(f.z), LUT, s_gctr, s_roff, G, lane);
        gather_one(f2key(f.w), LUT, s_gctr, s_roff, G, lane);
      }
    }
  }
  __syncthreads();

  // ---- threshold (block fallback only if its bin wasn't gathered) ----
  if (!s_thr_ok) {
    uint32_t bel;
    uint32_t key = global_select_key(sl, THRESH_RANK, HC1, HC2, Wsum, &bel);
    if (tid == 0) { s_thresh = key2f(key); s_cnlt = bel; }
    __syncthreads();
  }

  // ---- wave-0 select phase: thresh (fast path) + quantiles, no barriers ----
  if (tid < 64) {
    SelState st; st.curBin = -1; st.curB2 = -1;
    uint32_t cnlt;
    if (s_thr_ok) {
      bool ok; uint32_t bel;
      float th = wave_rank_value(THRESH_RANK, HC1, G, LUT, s_roff, s_rcnt,
                                 HC2, HL3, lane, &st, &ok, &bel);
      cnlt = bel;
      if (lane == 0) { s_thresh = th; s_cnlt = bel; }
    } else {
      cnlt = s_cnlt;
    }
    uint32_t n  = NPIX - cnlt;
    uint32_t t0 = cnlt;
    float nm1f = (float)n - 1.0f;
    int last = (int)nm1f;
    const float pp[3] = {0.25f, 0.5f, 0.75f};
    for (int qi = 0; qi < 3; ++qi) {
      float pos = pp[qi] * nm1f;
      float lof = floorf(pos);
      float fr = pos - lof;
      int lo_i = (int)lof;
      int hi_i = min(lo_i + 1, last);
      bool needB = (fr > 0.0f) && (hi_i != lo_i);
      bool okA, okB = true; uint32_t beld;
      float va = wave_rank_value(t0 + (uint32_t)lo_i, HC1, G, LUT, s_roff, s_rcnt,
                                 HC2, HL3, lane, &st, &okA, &beld);
      float vb = va;
      if (needB)
        vb = wave_rank_value(t0 + (uint32_t)hi_i, HC1, G, LUT, s_roff, s_rcnt,
                             HC2, HL3, lane, &st, &okB, &beld);
      if (lane == 0) {
        s_qA[qi] = va; s_qB[qi] = vb; s_qfr[qi] = fr; s_qdup[qi] = needB ? 0 : 1;
        s_qfb[qi * 2]     = okA ? 0xFFFFFFFFu : (t0 + (uint32_t)lo_i);
        s_qfb[qi * 2 + 1] = (needB && !okB) ? (t0 + (uint32_t)hi_i) : 0xFFFFFFFFu;
      }
    }
  }
  __syncthreads();

  // ---- block-wide fallbacks for un-gathered quantile ranks (rare) ----
  for (int si = 0; si < 6; ++si) {
    uint32_t r = s_qfb[si];
    if (r != 0xFFFFFFFFu) {
      uint32_t bel;
      uint32_t key = global_select_key(sl, r, HC1, HC2, Wsum, &bel);
      if (tid == 0) {
        if (si & 1) s_qB[si >> 1] = key2f(key); else s_qA[si >> 1] = key2f(key);
      }
      __syncthreads();
    }
  }

  const float thresh = s_thresh;
  const uint32_t n = NPIX - s_cnlt;
  const float vmax  = key2f(smaxkey);
  const float vminf = thresh;

  // ---- Pass D (fused): masked moments, |x|, centroid, hist16, gradient ----
  float rng = vmax - vminf;
  float denomf = (rng > 0.0f) ? rng : 1.0f;
  float sxl = 0, sx2l = 0, sx3l = 0, sx4l = 0, sabl = 0, sgl = 0, sg2l = 0;
  uint32_t syi = 0, sxi = 0;
  for (int c = 0; c < 4; ++c) {
    float4 cv[4];
#pragma unroll
    for (int j = 0; j < 4; ++j) cv[j] = sl4[tid + (c * 4 + j) * NTHREADS];
#pragma unroll
    for (int j = 0; j < 4; ++j) {
      int i4 = tid + (c * 4 + j) * NTHREADS;
      float4 v = cv[j];
      bool m0 = v.x >= thresh, m1 = v.y >= thresh, m2 = v.z >= thresh, m3 = v.w >= thresh;
      if (m0 | m1 | m2 | m3) {
        int y = i4 >> 6, xb = (i4 & 63) << 2;
        float4 up = sl4[(y > 0)   ? (i4 - 64) : i4];
        float4 dn = sl4[(y < 255) ? (i4 + 64) : i4];
        float lf = (xb > 0)   ? sl[4 * i4 - 1] : 0.0f;
        float rt = (xb < 252) ? sl[4 * i4 + 4] : 0.0f;
#define DOC(mc, vc, upc, dnc, lv, rv, xc)                                      \
        if (mc) {                                                              \
          float gy = (y == 0) ? (dnc - vc) : ((y == 255) ? (vc - upc) : 0.5f * (dnc - upc)); \
          int xx = xb + (xc);                                                  \
          float gx = (xx == 0) ? (rv - vc) : ((xx == 255) ? (vc - lv) : 0.5f * (rv - lv));   \
          float gm = sqrtf(gy * gy + gx * gx);                                 \
          sgl += gm; sg2l += gm * gm;                                          \
          float v2 = vc * vc;                                                  \
          sxl += vc; sx2l += v2; sx3l += v2 * vc; sx4l += v2 * v2;             \
          sabl += fabsf(vc);                                                   \
          syi += (uint32_t)y; sxi += (uint32_t)xx;                             \
          float bf = floorf((vc - vminf) / denomf * 16.0f);                    \
          int bin = (int)bf; bin = bin < 0 ? 0 : (bin > 15 ? 15 : bin);        \
          atomicAdd(&H16[(wid << 4) + bin], 1u);                               \
        }
        DOC(m0, v.x, up.x, dn.x, lf,  v.y, 0)
        DOC(m1, v.y, up.y, dn.y, v.x, v.z, 1)
        DOC(m2, v.z, up.z, dn.z, v.y, v.w, 2)
        DOC(m3, v.w, up.w, dn.w, v.z, rt,  3)
#undef DOC
      }
    }
  }

  // ---- fused 9-way f64 reduction: per-wave shuffle, one barrier, wave-0 tree ----
  double a[9] = {(double)sxl, (double)sx2l, (double)sx3l, (double)sx4l,
                 (double)sabl, (double)sgl, (double)sg2l, (double)syi, (double)sxi};
#pragma unroll
  for (int k = 0; k < 9; ++k)
    for (int d = 32; d > 0; d >>= 1) a[k] += __shfl_down(a[k], d);
  if (lane == 0) {
#pragma unroll
    for (int k = 0; k < 9; ++k) tmpD9[wid * 9 + k] = a[k];
  }
  __syncthreads();
  if (tid < 64) {
    double r0 = 0, r1 = 0, r2 = 0, r3 = 0, r4 = 0, r5 = 0, r6 = 0, r7 = 0, r8 = 0;
    if (lane < 16) {
      r0 = tmpD9[lane * 9 + 0]; r1 = tmpD9[lane * 9 + 1]; r2 = tmpD9[lane * 9 + 2];
      r3 = tmpD9[lane * 9 + 3]; r4 = tmpD9[lane * 9 + 4]; r5 = tmpD9[lane * 9 + 5];
      r6 = tmpD9[lane * 9 + 6]; r7 = tmpD9[lane * 9 + 7]; r8 = tmpD9[lane * 9 + 8];
    }
    for (int d = 8; d > 0; d >>= 1) {
      r0 += __shfl_down(r0, d); r1 += __shfl_down(r1, d); r2 += __shfl_down(r2, d);
      r3 += __shfl_down(r3, d); r4 += __shfl_down(r4, d); r5 += __shfl_down(r5, d);
      r6 += __shfl_down(r6, d); r7 += __shfl_down(r7, d); r8 += __shfl_down(r8, d);
    }
    if (lane == 0) {
      s_red[0] = r0; s_red[1] = r1; s_red[2] = r2; s_red[3] = r3; s_red[4] = r4;
      s_red[5] = r5; s_red[6] = r6; s_red[7] = r7; s_red[8] = r8;
    }
  }
  __syncthreads();

  // ---- finalize features (thread 0) ----
  if (tid == 0) {
    double sx = s_red[0], sx2 = s_red[1], sx3 = s_red[2], sx4 = s_red[3];
    double sab = s_red[4], sg = s_red[5], sg2 = s_red[6], syid = s_red[7], sxid = s_red[8];
    double dn = (double)n;
    double mean = sx / dn;
    double M2 = sx2 - sx * sx / dn;
    double std_ = sqrt(M2 / dn);
    double se = fmax(std_, 1e-6);
    double S3 = sx3 - 3.0 * mean * sx2 + 2.0 * dn * mean * mean * mean;
    double S4 = sx4 - 4.0 * mean * sx3 + 6.0 * mean * mean * sx2
                - 3.0 * dn * mean * mean * mean * mean;
    double skew = (S3 / dn) / (se * se * se);
    skew = fmin(fmax(skew, -50.0), 50.0);
    double kurt = (S4 / dn) / (se * se * se * se);
    kurt = fmin(fmax(kurt, 0.0), 100.0);
    double msq = sx2 / dn;
    double absmean = sab / dn;

    double ent = 0.0;
    double nden = fmax(dn, 1.0);
    for (int bi = 0; bi < 16; ++bi) {
      uint32_t hb = 0;
#pragma unroll
      for (int w = 0; w < 16; ++w) hb += H16[(w << 4) + bi];
      double p = fmax((double)hb / nden, 1e-6);
      ent -= p * log(p);
    }
    if (fabsf(vminf - vmax) <= 1e-8f + 1e-5f * fabsf(vmax)) ent = 0.0;

    double gmean = sg / dn;
    double gstd = sqrt(fmax(sg2 / dn - gmean * gmean, 0.0));
    double cy = (syid / dn) / 255.0;
    double cx = (sxid / dn) / 255.0;
    double frac = dn / (double)NPIX;

    float qv[3];
#pragma unroll
    for (int qi = 0; qi < 3; ++qi) {
      float A = s_qA[qi];
      float Bv = s_qdup[qi] ? A : s_qB[qi];
      float fr = s_qfr[qi];
      qv[qi] = A * (1.0f - fr) + Bv * fr;
    }

    float* fo = feats + (size_t)blockIdx.x * NFEAT;
    fo[0]  = (float)mean;  fo[1]  = (float)std_;  fo[2]  = vminf;       fo[3]  = vmax;
    fo[4]  = qv[0];        fo[5]  = qv[1];        fo[6]  = qv[2];       fo[7]  = (float)msq;
    fo[8]  = (float)ent;   fo[9]  = (float)skew;  fo[10] = (float)kurt; fo[11] = (float)frac;
    fo[12] = (float)gmean; fo[13] = (float)gstd;  fo[14] = (float)cy;   fo[15] = (float)cx;
    fo[16] = (float)frac;  fo[17] = (float)absmean;
  }
}

__global__ __launch_bounds__(EMB) void token_kernel(const float* __restrict__ feats,
                                                    const float* __restrict__ W,
                                                    const float* __restrict__ b,
                                                    const float* __restrict__ gamma,
                                                    const float* __restrict__ beta,
                                                    float* __restrict__ out,
                                                    float* __restrict__ maskout) {
  __shared__ float f[NFEAT];
  __shared__ float red[4];
  int s = blockIdx.x, e = threadIdx.x;
  if (e < NFEAT) f[e] = feats[(size_t)s * NFEAT + e];
  __syncthreads();
  float acc = b[e];
#pragma unroll
  for (int k = 0; k < NFEAT; ++k) acc += f[k] * W[k * EMB + e];
  int lane = e & 63, wd = e >> 6;
  float sum = acc;
  for (int d = 32; d > 0; d >>= 1) sum += __shfl_down(sum, d);
  if (lane == 0) red[wd] = sum;
  __syncthreads();
  float mu = (red[0] + red[1] + red[2] + red[3]) * (1.0f / EMB);
  float c = acc - mu;
  float s2 = c * c;
  for (int d = 32; d > 0; d >>= 1) s2 += __shfl_down(s2, d);
  __syncthreads();
  if (lane == 0) red[wd] = s2;
  __syncthreads();
  float var = (red[0] + red[1] + red[2] + red[3]) * (1.0f / EMB);
  float o = c / sqrtf(var + 1e-5f) * gamma[e] + beta[e];
  out[(size_t)s * EMB + e] = o;
  if (e == 0) maskout[s] = 0.0f;
}

extern "C" void kernel_launch(void* const* d_in, const int* in_sizes, int n_in,
                              void* d_out, int out_size, void* d_ws, size_t ws_size,
                              hipStream_t stream) {
  const float* vol   = (const float*)d_in[0];
  const float* W     = (const float*)d_in[1];
  const float* b     = (const float*)d_in[2];
  const float* gamma = (const float*)d_in[3];
  const float* beta  = (const float*)d_in[4];
  float* out = (float*)d_out;
  float* feats = (float*)d_ws;

  feat_kernel<<<NSLICES, NTHREADS, 0, stream>>>(vol, feats);
  token_kernel<<<NSLICES, EMB, 0, stream>>>(feats, W, b, gamma, beta,
                                            out, out + (size_t)NSLICES * EMB);
}

// Round 5
// 111.230 us; speedup vs baseline: 2.5618x; 2.5618x over previous
//
#include <hip/hip_runtime.h>
#include <stdint.h>

#define NPIX     65536
#define NTHREADS 1024
#define NSLICES  512
#define NFEAT    18
#define EMB      256
#define THRESH_RANK 52428u  // 0.8f*(65536-1) == 52428.0 exactly in f32 => fr == 0
#define NB       24         // l2 histogram slots (24*256*4B = 24 KB LDS)
#define IVMAX    4          // max bin intervals per Pass B round
#define EPT4     16         // float4 iterations per thread

// ---------- sortable key mapping (monotonic with float order) ----------
__device__ __forceinline__ uint32_t f2key(float f) {
  uint32_t u = __float_as_uint(f);
  return u ^ ((u & 0x80000000u) ? 0xFFFFFFFFu : 0x80000000u);
}
__device__ __forceinline__ float key2f(uint32_t k) {
  uint32_t u = (k & 0x80000000u) ? (k ^ 0x80000000u) : ~k;
  return __uint_as_float(u);
}

// block-wide inclusive prefix over 2048 bins (Pass A only)
__device__ void scan2048(uint32_t* H, uint32_t* Wsum) {
  int tid = threadIdx.x, lane = tid & 63, wid = tid >> 6;
  uint32_t a1 = H[2 * tid + 1];
  uint32_t v = H[2 * tid] + a1;
  for (int d = 1; d < 64; d <<= 1) {
    uint32_t t = __shfl_up(v, d);
    if (lane >= d) v += t;
  }
  if (lane == 63) Wsum[wid] = v;
  __syncthreads();
  uint32_t woff = 0;
  for (int w = 0; w < wid; ++w) woff += Wsum[w];
  v += woff;
  H[2 * tid + 1] = v;
  H[2 * tid]     = v - a1;
  __syncthreads();
}

// wave-synchronous find: smallest b with C[b] > r (inclusive prefix, 2048)
__device__ __forceinline__ int wfind2048(const uint32_t* C, uint32_t r, int lane) {
  unsigned long long m = __ballot(C[lane * 32 + 31] > r);
  int chunk = __builtin_ctzll(m);
  unsigned long long m2 = __ballot((lane < 32) && (C[chunk * 32 + lane] > r));
  int off = __builtin_ctzll(m2);
  return chunk * 32 + off;
}
// same over 256-entry inclusive prefix
__device__ __forceinline__ int wfind256(const uint32_t* P, uint32_t r, int lane) {
  unsigned long long m = __ballot(P[lane * 4 + 3] > r);
  int chunk = __builtin_ctzll(m);
  int off = 0;
  while (off < 3 && P[chunk * 4 + off] <= r) ++off;
  return chunk * 4 + off;
}
// wave-synchronous in-place inclusive scan of 256 bins
__device__ __forceinline__ void wscan256(uint32_t* H, int lane) {
  uint32_t h0 = H[lane * 4 + 0], h1 = H[lane * 4 + 1];
  uint32_t h2 = H[lane * 4 + 2], h3 = H[lane * 4 + 3];
  uint32_t s = h0 + h1 + h2 + h3, inc = s;
  for (int d = 1; d < 64; d <<= 1) { uint32_t o = __shfl_up(inc, d); if (lane >= d) inc += o; }
  uint32_t base = inc - s;
  H[lane * 4 + 0] = base + h0;
  H[lane * 4 + 1] = base + h0 + h1;
  H[lane * 4 + 2] = base + h0 + h1 + h2;
  H[lane * 4 + 3] = base + s;
}

// bin -> slot via interval table (wave-uniform LDS reads)
__device__ __forceinline__ int slotOf(uint32_t b, const uint32_t* ivLo, const uint32_t* ivHi,
                                      const uint32_t* ivS0, int niv) {
  for (int j = 0; j < niv; ++j)
    if (b >= ivLo[j] && b <= ivHi[j]) return (int)(ivS0[j] + b - ivLo[j]);
  return -1;
}

// lane0-scalar: merge ≤6 bins into ≤IVMAX intervals, assign slots
__device__ void plan_from_bins(int m, const uint32_t* pbin,
                               uint32_t* ivLo, uint32_t* ivHi, uint32_t* ivS0,
                               int* pniv, int* pnslots) {
  uint32_t b[6];
  for (int i = 0; i < m; ++i) b[i] = pbin[i];
  for (int i = 1; i < m; ++i) {
    uint32_t x = b[i]; int j = i - 1;
    while (j >= 0 && b[j] > x) { b[j + 1] = b[j]; --j; }
    b[j + 1] = x;
  }
  int niv = 0; uint32_t s0 = 0; int i = 0;
  while (i < m && niv < IVMAX) {
    uint32_t lo = b[i], hi = b[i]; ++i;
    while (i < m && b[i] <= hi + 1) { hi = max(hi, b[i]); ++i; }
    ivLo[niv] = lo; ivHi[niv] = hi; ivS0[niv] = s0;
    s0 += hi - lo + 1; ++niv;
  }
  for (int j = niv; j < IVMAX; ++j) { ivLo[j] = 0xFFFFu; ivHi[j] = 0u; ivS0[j] = 0u; }
  *pniv = niv; *pnslots = (int)s0;
}

__global__ __launch_bounds__(NTHREADS) void feat_kernel(const float* __restrict__ vol,
                                                        float* __restrict__ feats) {
  __shared__ uint32_t HC1[2048];        // l1 histogram -> inclusive prefix C1
  __shared__ uint32_t L2H[NB * 256];    // per-candidate-bin 256-bin l2 hists -> prefixes
  __shared__ uint32_t Wsum[16];
  __shared__ double   tmpD9[16 * 9];
  __shared__ double   s_red[9];
  __shared__ uint32_t H16[16 * 16];     // per-wave privatized entropy histogram
  __shared__ uint32_t smaxkey;
  __shared__ uint32_t s_ivLo[IVMAX], s_ivHi[IVMAX], s_ivS0[IVMAX];
  __shared__ int      s_niv, s_nslots;
  __shared__ float    s_thresh;
  __shared__ uint32_t s_cnlt;
  __shared__ float    s_qA[3], s_qB[3], s_qfr[3];
  __shared__ int      s_qdup[3];
  __shared__ uint32_t s_prank[6], s_pbin[6];
  __shared__ uint8_t  s_ptag[6];
  __shared__ int      s_npend;

  const int tid  = threadIdx.x;
  const int lane = tid & 63;
  const int wid  = tid >> 6;
  const float*  sl  = vol + (size_t)blockIdx.x * NPIX;
  const float4* sl4 = (const float4*)sl;

  // ---- Pass A: l1 histogram (key>>21) + global max ----
  HC1[2 * tid] = 0; HC1[2 * tid + 1] = 0;
  if (tid == 0) smaxkey = 0u;
  if (tid < 256) H16[tid] = 0u;
  __syncthreads();
  uint32_t mk = 0u;
#pragma unroll 4
  for (int t = 0; t < EPT4; ++t) {
    float4 f = sl4[tid + t * NTHREADS];
    uint32_t k0 = f2key(f.x), k1 = f2key(f.y), k2 = f2key(f.z), k3 = f2key(f.w);
    mk = max(mk, max(max(k0, k1), max(k2, k3)));
    atomicAdd(&HC1[k0 >> 21], 1u);
    atomicAdd(&HC1[k1 >> 21], 1u);
    atomicAdd(&HC1[k2 >> 21], 1u);
    atomicAdd(&HC1[k3 >> 21], 1u);
  }
  for (int d = 32; d > 0; d >>= 1) { uint32_t o = __shfl_down(mk, d); mk = max(mk, o); }
  if (lane == 0) atomicMax(&smaxkey, mk);
  __syncthreads();
  scan2048(HC1, Wsum);   // HC1 is now C1 (trailing barrier inside)

  // ---- round-1 planning (wave 0; lane 0 writes) ----
  if (tid < 64) {
    int b1t = wfind2048(HC1, THRESH_RANK, lane);
    uint32_t clo  = b1t ? HC1[b1t - 1] : 0u;
    uint32_t cmax = min(THRESH_RANK, HC1[b1t] - 1u);
    uint32_t rl[4], rh[4];
    rl[0] = (uint32_t)b1t; rh[0] = (uint32_t)b1t;   // threshold bin (as bin range)
    const float pp[3] = {0.25f, 0.5f, 0.75f};
#pragma unroll
    for (int qi = 0; qi < 3; ++qi) {
      float p = pp[qi];
      uint32_t rlo = clo  + (uint32_t)(int)floorf(p * ((float)(NPIX - clo)  - 1.0f));
      uint32_t rhi = cmax + (uint32_t)(int)floorf(p * ((float)(NPIX - cmax) - 1.0f)) + 1u;
      if (rhi > NPIX - 1u) rhi = NPIX - 1u;
      if (rlo > rhi) rlo = rhi;
      uint32_t ba = (uint32_t)wfind2048(HC1, rlo, lane);
      uint32_t bb = (uint32_t)wfind2048(HC1, rhi, lane);
      if (bb > ba + 5u) bb = ba + 5u;      // cap 6 bins/range; retry covers clips
      rl[qi + 1] = ba; rh[qi + 1] = bb;
    }
    if (lane == 0) {
      // sort 4 ranges by lo (threshold bin is the minimum -> always allocated first)
      for (int i = 1; i < 4; ++i) {
        uint32_t xl = rl[i], xh = rh[i]; int j = i - 1;
        while (j >= 0 && rl[j] > xl) { rl[j + 1] = rl[j]; rh[j + 1] = rh[j]; --j; }
        rl[j + 1] = xl; rh[j + 1] = xh;
      }
      int niv = 0; uint32_t s0 = 0; int i = 0;
      while (i < 4 && niv < IVMAX && s0 < NB) {
        uint32_t lo = rl[i], hi = rh[i]; ++i;
        while (i < 4 && rl[i] <= hi + 1u) { hi = max(hi, rh[i]); ++i; }
        uint32_t cnt = hi - lo + 1u;
        if (s0 + cnt > NB) { cnt = NB - s0; hi = lo + cnt - 1u; }
        s_ivLo[niv] = lo; s_ivHi[niv] = hi; s_ivS0[niv] = s0;
        s0 += cnt; ++niv;
      }
      for (int j = niv; j < IVMAX; ++j) { s_ivLo[j] = 0xFFFFu; s_ivHi[j] = 0u; s_ivS0[j] = 0u; }
      s_niv = niv; s_nslots = (int)s0;
    }
  }
  __syncthreads();

  // ================= Pass B (+ rare retry rounds) =================
  for (int round = 0; round < 4; ++round) {
    // zero used slots
    {
      int ns = s_nslots;
      for (int i = tid; i < ns * 256; i += NTHREADS) L2H[i] = 0u;
    }
    __syncthreads();
    // traversal: interval-filtered l2 histogram build
    {
      uint32_t lo0 = s_ivLo[0], hi0 = s_ivHi[0], s00 = s_ivS0[0];
      uint32_t lo1 = s_ivLo[1], hi1 = s_ivHi[1], s01 = s_ivS0[1];
      uint32_t lo2 = s_ivLo[2], hi2 = s_ivHi[2], s02 = s_ivS0[2];
      uint32_t lo3 = s_ivLo[3], hi3 = s_ivHi[3], s03 = s_ivS0[3];
#pragma unroll 4
      for (int t = 0; t < EPT4; ++t) {
        float4 f = sl4[tid + t * NTHREADS];
#define PB(vv)                                                                  \
        { uint32_t k = f2key(vv); uint32_t b = k >> 21; uint32_t l2 = (k >> 13) & 255u; \
          if      (b >= lo0 && b <= hi0) atomicAdd(&L2H[(s00 + b - lo0) * 256 + l2], 1u); \
          else if (b >= lo1 && b <= hi1) atomicAdd(&L2H[(s01 + b - lo1) * 256 + l2], 1u); \
          else if (b >= lo2 && b <= hi2) atomicAdd(&L2H[(s02 + b - lo2) * 256 + l2], 1u); \
          else if (b >= lo3 && b <= hi3) atomicAdd(&L2H[(s03 + b - lo3) * 256 + l2], 1u); }
        PB(f.x) PB(f.y) PB(f.z) PB(f.w)
#undef PB
      }
    }
    __syncthreads();
    // scan each slot's 256-bin histogram (one wave per slot, round-robin)
    {
      int ns = s_nslots;
      for (int s = wid; s < ns; s += 16) wscan256(&L2H[s * 256], lane);
    }
    __syncthreads();

    // ---- resolve on wave 0 ----
    if (tid < 64) {
      int niv = s_niv;
      if (round == 0) {
        // threshold (bin guaranteed in plan)
        int b1t = wfind2048(HC1, THRESH_RANK, lane);
        uint32_t below = b1t ? HC1[b1t - 1] : 0u;
        int sl_ = slotOf((uint32_t)b1t, s_ivLo, s_ivHi, s_ivS0, niv);
        const uint32_t* P = &L2H[sl_ * 256];
        int b2 = wfind256(P, THRESH_RANK - below, lane);
        uint32_t cnlt = below + (b2 ? P[b2 - 1] : 0u);
        float th = key2f(((uint32_t)b1t << 21) | ((uint32_t)b2 << 13));
        if (lane == 0) { s_thresh = th; s_cnlt = cnlt; }
        uint32_t n = NPIX - cnlt, t0 = cnlt;
        float nm1f = (float)n - 1.0f;
        int last = (int)nm1f;
        const float pp[3] = {0.25f, 0.5f, 0.75f};
        int np = 0;
        for (int qi = 0; qi < 3; ++qi) {
          float pos = pp[qi] * nm1f;
          float lof = floorf(pos);
          float fr = pos - lof;
          int lo_i = (int)lof;
          int hi_i = min(lo_i + 1, last);
          bool needB = (fr > 0.0f) && (hi_i != lo_i);
          if (lane == 0) { s_qfr[qi] = fr; s_qdup[qi] = needB ? 0 : 1; }
          // rank A
          {
            uint32_t r = t0 + (uint32_t)lo_i;
            int b = wfind2048(HC1, r, lane);
            uint32_t bw = b ? HC1[b - 1] : 0u;
            int sq = slotOf((uint32_t)b, s_ivLo, s_ivHi, s_ivS0, niv);
            if (sq >= 0) {
              const uint32_t* Pq = &L2H[sq * 256];
              int b2q = wfind256(Pq, r - bw, lane);
              float v = key2f(((uint32_t)b << 21) | ((uint32_t)b2q << 13));
              if (lane == 0) { s_qA[qi] = v; s_qB[qi] = v; }
            } else {
              if (lane == 0) { s_prank[np] = r; s_ptag[np] = (uint8_t)(qi * 2); s_pbin[np] = (uint32_t)b; }
              ++np;
            }
          }
          if (needB) {
            uint32_t r = t0 + (uint32_t)hi_i;
            int b = wfind2048(HC1, r, lane);
            uint32_t bw = b ? HC1[b - 1] : 0u;
            int sq = slotOf((uint32_t)b, s_ivLo, s_ivHi, s_ivS0, niv);
            if (sq >= 0) {
              const uint32_t* Pq = &L2H[sq * 256];
              int b2q = wfind256(Pq, r - bw, lane);
              float v = key2f(((uint32_t)b << 21) | ((uint32_t)b2q << 13));
              if (lane == 0) s_qB[qi] = v;
            } else {
              if (lane == 0) { s_prank[np] = r; s_ptag[np] = (uint8_t)(qi * 2 + 1); s_pbin[np] = (uint32_t)b; }
              ++np;
            }
          }
        }
        if (lane == 0) {
          s_npend = np;
          if (np > 0) plan_from_bins(np, s_pbin, s_ivLo, s_ivHi, s_ivS0, &s_niv, &s_nslots);
        }
      } else {
        // retry: resolve pending ranks
        int np = s_npend, newnp = 0;
        for (int i = 0; i < np; ++i) {
          uint32_t r = s_prank[i];
          int tg = s_ptag[i];
          int b = wfind2048(HC1, r, lane);
          uint32_t bw = b ? HC1[b - 1] : 0u;
          int sq = slotOf((uint32_t)b, s_ivLo, s_ivHi, s_ivS0, niv);
          if (sq >= 0) {
            const uint32_t* Pq = &L2H[sq * 256];
            int b2q = wfind256(Pq, r - bw, lane);
            float v = key2f(((uint32_t)b << 21) | ((uint32_t)b2q << 13));
            if (lane == 0) { if (tg & 1) s_qB[tg >> 1] = v; else s_qA[tg >> 1] = v; }
          } else {
            if (lane == 0) { s_prank[newnp] = r; s_ptag[newnp] = (uint8_t)tg; s_pbin[newnp] = (uint32_t)b; }
            ++newnp;
          }
        }
        if (lane == 0) {
          s_npend = newnp;
          if (newnp > 0) plan_from_bins(newnp, s_pbin, s_ivLo, s_ivHi, s_ivS0, &s_niv, &s_nslots);
        }
      }
    }
    __syncthreads();
    if (s_npend == 0) break;
    __syncthreads();
  }

  const float thresh = s_thresh;
  const uint32_t n = NPIX - s_cnlt;
  const float vmax  = key2f(smaxkey);
  const float vminf = thresh;

  // ---- Pass D (fused): masked moments, |x|, centroid, hist16, gradient ----
  float rng = vmax - vminf;
  float denomf = (rng > 0.0f) ? rng : 1.0f;
  float sxl = 0, sx2l = 0, sx3l = 0, sx4l = 0, sabl = 0, sgl = 0, sg2l = 0;
  uint32_t syi = 0, sxi = 0;
#pragma unroll 4
  for (int t = 0; t < EPT4; ++t) {
    int i4 = tid + t * NTHREADS;
    float4 v = sl4[i4];
    bool m0 = v.x >= thresh, m1 = v.y >= thresh, m2 = v.z >= thresh, m3 = v.w >= thresh;
    if (m0 | m1 | m2 | m3) {
      int y = i4 >> 6, xb = (i4 & 63) << 2;
      float4 up = sl4[(y > 0)   ? (i4 - 64) : i4];
      float4 dn = sl4[(y < 255) ? (i4 + 64) : i4];
      float lf = (xb > 0)   ? sl[4 * i4 - 1] : 0.0f;
      float rt = (xb < 252) ? sl[4 * i4 + 4] : 0.0f;
#define DOC(mc, vc, upc, dnc, lv, rv, xc)                                      \
      if (mc) {                                                                \
        float gy = (y == 0) ? (dnc - vc) : ((y == 255) ? (vc - upc) : 0.5f * (dnc - upc)); \
        int xx = xb + (xc);                                                    \
        float gx = (xx == 0) ? (rv - vc) : ((xx == 255) ? (vc - lv) : 0.5f * (rv - lv));   \
        float gm = sqrtf(gy * gy + gx * gx);                                   \
        sgl += gm; sg2l += gm * gm;                                            \
        float v2 = vc * vc;                                                    \
        sxl += vc; sx2l += v2; sx3l += v2 * vc; sx4l += v2 * v2;               \
        sabl += fabsf(vc);                                                     \
        syi += (uint32_t)y; sxi += (uint32_t)xx;                               \
        float bf = floorf((vc - vminf) / denomf * 16.0f);                      \
        int bin = (int)bf; bin = bin < 0 ? 0 : (bin > 15 ? 15 : bin);          \
        atomicAdd(&H16[(wid << 4) + bin], 1u);                                 \
      }
      DOC(m0, v.x, up.x, dn.x, lf,  v.y, 0)
      DOC(m1, v.y, up.y, dn.y, v.x, v.z, 1)
      DOC(m2, v.z, up.z, dn.z, v.y, v.w, 2)
      DOC(m3, v.w, up.w, dn.w, v.z, rt,  3)
#undef DOC
    }
  }

  // ---- fused 9-way f64 reduction ----
  double a[9] = {(double)sxl, (double)sx2l, (double)sx3l, (double)sx4l,
                 (double)sabl, (double)sgl, (double)sg2l, (double)syi, (double)sxi};
#pragma unroll
  for (int k = 0; k < 9; ++k)
    for (int d = 32; d > 0; d >>= 1) a[k] += __shfl_down(a[k], d);
  if (lane == 0) {
#pragma unroll
    for (int k = 0; k < 9; ++k) tmpD9[wid * 9 + k] = a[k];
  }
  __syncthreads();
  if (tid < 64) {
    double r0 = 0, r1 = 0, r2 = 0, r3 = 0, r4 = 0, r5 = 0, r6 = 0, r7 = 0, r8 = 0;
    if (lane < 16) {
      r0 = tmpD9[lane * 9 + 0]; r1 = tmpD9[lane * 9 + 1]; r2 = tmpD9[lane * 9 + 2];
      r3 = tmpD9[lane * 9 + 3]; r4 = tmpD9[lane * 9 + 4]; r5 = tmpD9[lane * 9 + 5];
      r6 = tmpD9[lane * 9 + 6]; r7 = tmpD9[lane * 9 + 7]; r8 = tmpD9[lane * 9 + 8];
    }
    for (int d = 8; d > 0; d >>= 1) {
      r0 += __shfl_down(r0, d); r1 += __shfl_down(r1, d); r2 += __shfl_down(r2, d);
      r3 += __shfl_down(r3, d); r4 += __shfl_down(r4, d); r5 += __shfl_down(r5, d);
      r6 += __shfl_down(r6, d); r7 += __shfl_down(r7, d); r8 += __shfl_down(r8, d);
    }
    if (lane == 0) {
      s_red[0] = r0; s_red[1] = r1; s_red[2] = r2; s_red[3] = r3; s_red[4] = r4;
      s_red[5] = r5; s_red[6] = r6; s_red[7] = r7; s_red[8] = r8;
    }
  }
  __syncthreads();

  // ---- finalize features (thread 0) ----
  if (tid == 0) {
    double sx = s_red[0], sx2 = s_red[1], sx3 = s_red[2], sx4 = s_red[3];
    double sab = s_red[4], sg = s_red[5], sg2 = s_red[6], syid = s_red[7], sxid = s_red[8];
    double dn = (double)n;
    double mean = sx / dn;
    double M2 = sx2 - sx * sx / dn;
    double std_ = sqrt(M2 / dn);
    double se = fmax(std_, 1e-6);
    double S3 = sx3 - 3.0 * mean * sx2 + 2.0 * dn * mean * mean * mean;
    double S4 = sx4 - 4.0 * mean * sx3 + 6.0 * mean * mean * sx2
                - 3.0 * dn * mean * mean * mean * mean;
    double skew = (S3 / dn) / (se * se * se);
    skew = fmin(fmax(skew, -50.0), 50.0);
    double kurt = (S4 / dn) / (se * se * se * se);
    kurt = fmin(fmax(kurt, 0.0), 100.0);
    double msq = sx2 / dn;
    double absmean = sab / dn;

    double ent = 0.0;
    double nden = fmax(dn, 1.0);
    for (int bi = 0; bi < 16; ++bi) {
      uint32_t hb = 0;
#pragma unroll
      for (int w = 0; w < 16; ++w) hb += H16[(w << 4) + bi];
      double p = fmax((double)hb / nden, 1e-6);
      ent -= p * log(p);
    }
    if (fabsf(vminf - vmax) <= 1e-8f + 1e-5f * fabsf(vmax)) ent = 0.0;

    double gmean = sg / dn;
    double gstd = sqrt(fmax(sg2 / dn - gmean * gmean, 0.0));
    double cy = (syid / dn) / 255.0;
    double cx = (sxid / dn) / 255.0;
    double frac = dn / (double)NPIX;

    float qv[3];
#pragma unroll
    for (int qi = 0; qi < 3; ++qi) {
      float A = s_qA[qi];
      float Bv = s_qdup[qi] ? A : s_qB[qi];
      float fr = s_qfr[qi];
      qv[qi] = A * (1.0f - fr) + Bv * fr;
    }

    float* fo = feats + (size_t)blockIdx.x * NFEAT;
    fo[0]  = (float)mean;  fo[1]  = (float)std_;  fo[2]  = vminf;       fo[3]  = vmax;
    fo[4]  = qv[0];        fo[5]  = qv[1];        fo[6]  = qv[2];       fo[7]  = (float)msq;
    fo[8]  = (float)ent;   fo[9]  = (float)skew;  fo[10] = (float)kurt; fo[11] = (float)frac;
    fo[12] = (float)gmean; fo[13] = (float)gstd;  fo[14] = (float)cy;   fo[15] = (float)cx;
    fo[16] = (float)frac;  fo[17] = (float)absmean;
  }
}

__global__ __launch_bounds__(EMB) void token_kernel(const float* __restrict__ feats,
                                                    const float* __restrict__ W,
                                                    const float* __restrict__ b,
                                                    const float* __restrict__ gamma,
                                                    const float* __restrict__ beta,
                                                    float* __restrict__ out,
                                                    float* __restrict__ maskout) {
  __shared__ float f[NFEAT];
  __shared__ float red[4];
  int s = blockIdx.x, e = threadIdx.x;
  if (e < NFEAT) f[e] = feats[(size_t)s * NFEAT + e];
  __syncthreads();
  float acc = b[e];
#pragma unroll
  for (int k = 0; k < NFEAT; ++k) acc += f[k] * W[k * EMB + e];
  int lane = e & 63, wd = e >> 6;
  float sum = acc;
  for (int d = 32; d > 0; d >>= 1) sum += __shfl_down(sum, d);
  if (lane == 0) red[wd] = sum;
  __syncthreads();
  float mu = (red[0] + red[1] + red[2] + red[3]) * (1.0f / EMB);
  float c = acc - mu;
  float s2 = c * c;
  for (int d = 32; d > 0; d >>= 1) s2 += __shfl_down(s2, d);
  __syncthreads();
  if (lane == 0) red[wd] = s2;
  __syncthreads();
  float var = (red[0] + red[1] + red[2] + red[3]) * (1.0f / EMB);
  float o = c / sqrtf(var + 1e-5f) * gamma[e] + beta[e];
  out[(size_t)s * EMB + e] = o;
  if (e == 0) maskout[s] = 0.0f;
}

extern "C" void kernel_launch(void* const* d_in, const int* in_sizes, int n_in,
                              void* d_out, int out_size, void* d_ws, size_t ws_size,
                              hipStream_t stream) {
  const float* vol   = (const float*)d_in[0];
  const float* W     = (const float*)d_in[1];
  const float* b     = (const float*)d_in[2];
  const float* gamma = (const float*)d_in[3];
  const float* beta  = (const float*)d_in[4];
  float* out = (float*)d_out;
  float* feats = (float*)d_ws;

  feat_kernel<<<NSLICES, NTHREADS, 0, stream>>>(vol, feats);
  token_kernel<<<NSLICES, EMB, 0, stream>>>(feats, W, b, gamma, beta,
                                            out, out + (size_t)NSLICES * EMB);
}